// Round 1
// baseline (2362.456 us; speedup 1.0000x reference)
//
#include <hip/hip_runtime.h>

#define HIPPO_N 256
#define HIPPO_L 2048

// Single-wave sequential scan exploiting the HiPPO-LegS structure:
//   A[i,j] = -T_i T_j (i>j), A[i,i] = -(i+1), T_i = sqrt(2i+1), B = T
//   step:  c' = (I - A/2t)^{-1} ( (I + A/2t) c + (T/t) u_t )
//   pred_t = f_t * (g . c') / (2t - N^2) + ((2t + N^2)/(2t - N^2)) u_t
//   g[j] = -T_j * ((j+1) + N^2 - (j+1)^2)
// Each of 64 lanes owns 4 contiguous rows. Per step:
//   1) exclusive prefix P_i = sum_{j<i} T_j c_j            (wave scan)
//   2) vt_i = c_i (2t-(i+1)) - T_i P_i + 2 u T_i           (elementwise)
//   3) Q-recurrence Q_{i+1} = a_i Q_i + e_i, a_i=(2t-i)rho_i, e_i=T_i vt_i rho_i,
//      rho_i = 1/(2t+i+1)                                   (wave affine scan)
//   4) x_i = (vt_i - T_i Q_i) rho_i  -> new c; s = sum g_i x_i (wave reduce)
__global__ __launch_bounds__(64, 1)
void hippo_scan_kernel(const float* __restrict__ u, float* __restrict__ out) {
    const int lane = threadIdx.x & 63;
    const int i0 = lane * 4;

    float T[4], g[4], fi1[4];
#pragma unroll
    for (int k = 0; k < 4; ++k) {
        const float fi = (float)(i0 + k);
        const float ip1 = fi + 1.0f;
        T[k] = sqrtf(2.0f * fi + 1.0f);
        fi1[k] = ip1;
        g[k] = -T[k] * (ip1 + 65536.0f - ip1 * ip1);
    }

    float c[4] = {0.f, 0.f, 0.f, 0.f};
    float u_nxt = u[0];

    for (int t = 1; t <= HIPPO_L; ++t) {
        const float u_t = u_nxt;
        u_nxt = u[t < HIPPO_L ? t : HIPPO_L - 1];  // prefetch next step's input
        const float two_t = 2.0f * (float)t;

        // ---- 1) exclusive prefix of T*c across all 256 rows ----
        float pl[4];
        float run = 0.f;
#pragma unroll
        for (int k = 0; k < 4; ++k) {
            pl[k] = run;
            run += T[k] * c[k];
        }
        float inc = run;
#pragma unroll
        for (int d = 1; d < 64; d <<= 1) {
            float w = __shfl_up(inc, d, 64);
            if (lane >= d) inc += w;
        }
        const float Pbase = inc - run;  // exclusive across lanes

        // ---- 2) vt and per-row solve coefficients ----
        float vt[4], rho[4];
#pragma unroll
        for (int k = 0; k < 4; ++k) {
            const float P = Pbase + pl[k];
            vt[k] = c[k] * (two_t - fi1[k]) - T[k] * P + 2.0f * u_t * T[k];
            rho[k] = 1.0f / (two_t + fi1[k]);
        }

        // ---- 3) affine scan for Q (triangular solve running sum) ----
        // local exclusive composition within the lane's 4 rows
        float al[4], el[4];
        float Aacc = 1.f, Eacc = 0.f;
#pragma unroll
        for (int k = 0; k < 4; ++k) {
            al[k] = Aacc;
            el[k] = Eacc;
            const float a = (two_t - (fi1[k] - 1.0f)) * rho[k];  // (2t - i) * rho_i
            const float e = T[k] * vt[k] * rho[k];
            Eacc = a * Eacc + e;
            Aacc = a * Aacc;
        }
        // wave inclusive scan of affine pairs (compose lane segments in order)
        float Ai = Aacc, Ei = Eacc;
#pragma unroll
        for (int d = 1; d < 64; d <<= 1) {
            float Aw = __shfl_up(Ai, d, 64);
            float Ew = __shfl_up(Ei, d, 64);
            if (lane >= d) {
                Ei = Ai * Ew + Ei;
                Ai = Ai * Aw;
            }
        }
        // Q at this lane's first row: composition of all earlier lanes applied to 0
        float Qs = __shfl_up(Ei, 1, 64);
        if (lane == 0) Qs = 0.f;

        // ---- 4) solve rows, update state, output functional ----
        float s = 0.f;
#pragma unroll
        for (int k = 0; k < 4; ++k) {
            const float Q = al[k] * Qs + el[k];
            const float x = (vt[k] - T[k] * Q) * rho[k];
            c[k] = x;
            s += g[k] * x;
        }
#pragma unroll
        for (int d = 32; d >= 1; d >>= 1) s += __shfl_xor(s, d, 64);

        if (lane == 0) {
            const float denom = two_t - 65536.0f;
            const float f = (t == 1) ? 1.0f : 2.0f;
            out[t - 1] = f * (s / denom) + ((two_t + 65536.0f) / denom) * u_t;
        }
    }
}

extern "C" void kernel_launch(void* const* d_in, const int* in_sizes, int n_in,
                              void* d_out, int out_size, void* d_ws, size_t ws_size,
                              hipStream_t stream) {
    (void)in_sizes; (void)n_in; (void)d_ws; (void)ws_size; (void)out_size;
    const float* u = (const float*)d_in[0];
    float* out = (float*)d_out;
    hippo_scan_kernel<<<dim3(1), dim3(64), 0, stream>>>(u, out);
}

// Round 5
// 937.143 us; speedup vs baseline: 2.5209x; 2.5209x over previous
//
#include <hip/hip_runtime.h>

#define HIPPO_N 256
#define HIPPO_L 2048
#define CHUNKS  16
#define CSTEPS  128   // HIPPO_L / CHUNKS
#define NCOLS   257   // 256 basis columns + 1 u-driven column

// workspace layout (float offsets)
#define WS_PHI    0                                   // [CHUNKS][N][N]  Phi[g][j][i] (col-major per chunk)
#define WS_Y0     (CHUNKS * HIPPO_N * HIPPO_N)        // [CHUNKS][N]
#define WS_R      (WS_Y0 + CHUNKS * HIPPO_N)          // [L][N]  R[t][j]
#define WS_PRED0  (WS_R + HIPPO_L * HIPPO_N)          // [L]
#define WS_CIN    (WS_PRED0 + HIPPO_L)                // [CHUNKS][N]
#define WS_TOTAL  (WS_CIN + CHUNKS * HIPPO_N)

// ---------------------------------------------------------------------------
// Structured HiPPO-LegS step (validated round 1):
//   A[i,j] = -T_i T_j (i>j), A[i,i]=-(i+1), T_i=sqrt(2i+1), B=T
//   c' = (I - A/2t)^{-1}((I + A/2t) c + (T/t) u)
//   pred = f_t (g.c')/(2t-N^2) + ((2t+N^2)/(2t-N^2)) u,  g_j=-T_j((j+1)+N^2-(j+1)^2)
// Per wave: 4 rows/lane; prefix scan (P), affine scan (Q), reduce (g.c').
// ---------------------------------------------------------------------------

// Phase 1: one wave = (chunk g, column j). Basis columns propagate e_j with
// u=0 (linear map -> Phi column + R sensitivities); column j==256 propagates
// the zero state with real u (-> y0 + pred0 incl. direct term).
__global__ __launch_bounds__(256, 1)
void hippo_phase1(const float* __restrict__ u, float* __restrict__ ws) {
    const int lane = threadIdx.x & 63;
    const int wave = threadIdx.x >> 6;
    const int task = blockIdx.x * 4 + wave;
    if (task >= CHUNKS * NCOLS) return;
    const int g = task / NCOLS;
    const int j = task - g * NCOLS;
    const bool is_u = (j == HIPPO_N);
    const int i0 = lane * 4;

    float T[4], gv[4], fi1[4];
#pragma unroll
    for (int k = 0; k < 4; ++k) {
        const float fi = (float)(i0 + k);
        const float ip1 = fi + 1.0f;
        T[k] = sqrtf(2.0f * fi + 1.0f);
        fi1[k] = ip1;
        gv[k] = -T[k] * (ip1 + 65536.0f - ip1 * ip1);
    }

    float c[4];
#pragma unroll
    for (int k = 0; k < 4; ++k) c[k] = (!is_u && (i0 + k) == j) ? 1.0f : 0.0f;

    const int tbase = g * CSTEPS;  // t = tbase + tl + 1
    float u_nxt = is_u ? u[tbase] : 0.0f;

    for (int tl = 0; tl < CSTEPS; ++tl) {
        const int t = tbase + tl + 1;
        const float u_t = u_nxt;
        if (is_u) {
            const int nxt = tbase + tl + 1;
            u_nxt = u[nxt < HIPPO_L ? nxt : HIPPO_L - 1];
        }
        const float two_t = 2.0f * (float)t;

        // 1) exclusive prefix of T*c over 256 rows
        float pl[4];
        float run = 0.f;
#pragma unroll
        for (int k = 0; k < 4; ++k) { pl[k] = run; run += T[k] * c[k]; }
        float inc = run;
#pragma unroll
        for (int d = 1; d < 64; d <<= 1) {
            float w = __shfl_up(inc, d, 64);
            if (lane >= d) inc += w;
        }
        const float Pbase = inc - run;

        // 2) vt, rho
        float vt[4], rho[4];
#pragma unroll
        for (int k = 0; k < 4; ++k) {
            const float P = Pbase + pl[k];
            vt[k] = c[k] * (two_t - fi1[k]) - T[k] * P + 2.0f * u_t * T[k];
            rho[k] = 1.0f / (two_t + fi1[k]);
        }

        // 3) affine scan for Q (triangular solve)
        float al[4], el[4];
        float Aacc = 1.f, Eacc = 0.f;
#pragma unroll
        for (int k = 0; k < 4; ++k) {
            al[k] = Aacc; el[k] = Eacc;
            const float a = (two_t - (fi1[k] - 1.0f)) * rho[k];
            const float e = T[k] * vt[k] * rho[k];
            Eacc = a * Eacc + e;
            Aacc = a * Aacc;
        }
        float Ai = Aacc, Ei = Eacc;
#pragma unroll
        for (int d = 1; d < 64; d <<= 1) {
            float Aw = __shfl_up(Ai, d, 64);
            float Ew = __shfl_up(Ei, d, 64);
            if (lane >= d) { Ei = Ai * Ew + Ei; Ai = Ai * Aw; }
        }
        float Qs = __shfl_up(Ei, 1, 64);
        if (lane == 0) Qs = 0.f;

        // 4) solve, update state, output functional
        float s = 0.f;
#pragma unroll
        for (int k = 0; k < 4; ++k) {
            const float Q = al[k] * Qs + el[k];
            const float x = (vt[k] - T[k] * Q) * rho[k];
            c[k] = x;
            s += gv[k] * x;
        }
#pragma unroll
        for (int d = 32; d >= 1; d >>= 1) s += __shfl_xor(s, d, 64);

        if (lane == 0) {
            const float denom = two_t - 65536.0f;
            const float f = (t == 1) ? 1.0f : 2.0f;
            const float val = f * (s / denom);
            if (is_u)
                ws[WS_PRED0 + tbase + tl] = val + ((two_t + 65536.0f) / denom) * u_t;
            else
                ws[WS_R + (size_t)(tbase + tl) * HIPPO_N + j] = val;
        }
    }

    // final chunk state -> Phi column / y0
    float4 cv; cv.x = c[0]; cv.y = c[1]; cv.z = c[2]; cv.w = c[3];
    if (is_u)
        *(float4*)(ws + WS_Y0 + g * HIPPO_N + i0) = cv;
    else
        *(float4*)(ws + WS_PHI + ((size_t)(g * HIPPO_N + j)) * HIPPO_N + i0) = cv;
}

// Phase 2: serial chunk composition, cin[g+1] = Phi_g cin[g] + y0[g].
__global__ __launch_bounds__(256, 1)
void hippo_phase2(float* __restrict__ ws) {
    __shared__ float cs[HIPPO_N];
    const int i = threadIdx.x;
    float c = 0.f;
    for (int g = 0; g < CHUNKS; ++g) {
        ws[WS_CIN + g * HIPPO_N + i] = c;
        cs[i] = c;
        __syncthreads();
        if (g < CHUNKS - 1) {
            const float* P = ws + WS_PHI + (size_t)g * HIPPO_N * HIPPO_N + i;
            float acc = ws[WS_Y0 + g * HIPPO_N + i];
#pragma unroll 8
            for (int jj = 0; jj < HIPPO_N; ++jj)
                acc += P[(size_t)jj * HIPPO_N] * cs[jj];
            c = acc;
        }
        __syncthreads();
    }
}

// Phase 3: pred_t = pred0_t + R[t,:] . cin[chunk(t)]
__global__ __launch_bounds__(256, 1)
void hippo_phase3(float* __restrict__ out, const float* __restrict__ ws) {
    const int lane = threadIdx.x & 63;
    const int wave = threadIdx.x >> 6;
    const int t = blockIdx.x * 4 + wave;
    if (t >= HIPPO_L) return;
    const int g = t / CSTEPS;
    const float* Rr = ws + WS_R + (size_t)t * HIPPO_N;
    const float* ci = ws + WS_CIN + g * HIPPO_N;
    const int i0 = lane * 4;
    const float4 r = *(const float4*)(Rr + i0);
    const float4 cv = *(const float4*)(ci + i0);
    float s = r.x * cv.x + r.y * cv.y + r.z * cv.z + r.w * cv.w;
#pragma unroll
    for (int d = 32; d >= 1; d >>= 1) s += __shfl_xor(s, d, 64);
    if (lane == 0) out[t] = ws[WS_PRED0 + t] + s;
}

// ---------------------------------------------------------------------------
// Fallback: round-1 single-wave serial scan (used only if ws too small).
// ---------------------------------------------------------------------------
__global__ __launch_bounds__(64, 1)
void hippo_scan_serial(const float* __restrict__ u, float* __restrict__ out) {
    const int lane = threadIdx.x & 63;
    const int i0 = lane * 4;
    float T[4], gv[4], fi1[4];
#pragma unroll
    for (int k = 0; k < 4; ++k) {
        const float fi = (float)(i0 + k);
        const float ip1 = fi + 1.0f;
        T[k] = sqrtf(2.0f * fi + 1.0f);
        fi1[k] = ip1;
        gv[k] = -T[k] * (ip1 + 65536.0f - ip1 * ip1);
    }
    float c[4] = {0.f, 0.f, 0.f, 0.f};
    float u_nxt = u[0];
    for (int t = 1; t <= HIPPO_L; ++t) {
        const float u_t = u_nxt;
        u_nxt = u[t < HIPPO_L ? t : HIPPO_L - 1];
        const float two_t = 2.0f * (float)t;
        float pl[4]; float run = 0.f;
#pragma unroll
        for (int k = 0; k < 4; ++k) { pl[k] = run; run += T[k] * c[k]; }
        float inc = run;
#pragma unroll
        for (int d = 1; d < 64; d <<= 1) {
            float w = __shfl_up(inc, d, 64);
            if (lane >= d) inc += w;
        }
        const float Pbase = inc - run;
        float vt[4], rho[4];
#pragma unroll
        for (int k = 0; k < 4; ++k) {
            const float P = Pbase + pl[k];
            vt[k] = c[k] * (two_t - fi1[k]) - T[k] * P + 2.0f * u_t * T[k];
            rho[k] = 1.0f / (two_t + fi1[k]);
        }
        float al[4], el[4]; float Aacc = 1.f, Eacc = 0.f;
#pragma unroll
        for (int k = 0; k < 4; ++k) {
            al[k] = Aacc; el[k] = Eacc;
            const float a = (two_t - (fi1[k] - 1.0f)) * rho[k];
            const float e = T[k] * vt[k] * rho[k];
            Eacc = a * Eacc + e; Aacc = a * Aacc;
        }
        float Ai = Aacc, Ei = Eacc;
#pragma unroll
        for (int d = 1; d < 64; d <<= 1) {
            float Aw = __shfl_up(Ai, d, 64);
            float Ew = __shfl_up(Ei, d, 64);
            if (lane >= d) { Ei = Ai * Ew + Ei; Ai = Ai * Aw; }
        }
        float Qs = __shfl_up(Ei, 1, 64);
        if (lane == 0) Qs = 0.f;
        float s = 0.f;
#pragma unroll
        for (int k = 0; k < 4; ++k) {
            const float Q = al[k] * Qs + el[k];
            const float x = (vt[k] - T[k] * Q) * rho[k];
            c[k] = x; s += gv[k] * x;
        }
#pragma unroll
        for (int d = 32; d >= 1; d >>= 1) s += __shfl_xor(s, d, 64);
        if (lane == 0) {
            const float denom = two_t - 65536.0f;
            const float f = (t == 1) ? 1.0f : 2.0f;
            out[t - 1] = f * (s / denom) + ((two_t + 65536.0f) / denom) * u_t;
        }
    }
}

extern "C" void kernel_launch(void* const* d_in, const int* in_sizes, int n_in,
                              void* d_out, int out_size, void* d_ws, size_t ws_size,
                              hipStream_t stream) {
    (void)in_sizes; (void)n_in; (void)out_size;
    const float* u = (const float*)d_in[0];
    float* out = (float*)d_out;

    if (ws_size < (size_t)WS_TOTAL * sizeof(float)) {
        hippo_scan_serial<<<dim3(1), dim3(64), 0, stream>>>(u, out);
        return;
    }
    float* ws = (float*)d_ws;
    const int p1_blocks = (CHUNKS * NCOLS + 3) / 4;  // 4 waves per block
    hippo_phase1<<<dim3(p1_blocks), dim3(256), 0, stream>>>(u, ws);
    hippo_phase2<<<dim3(1), dim3(256), 0, stream>>>(ws);
    hippo_phase3<<<dim3(HIPPO_L / 4), dim3(256), 0, stream>>>(out, ws);
}

// Round 6
// 871.713 us; speedup vs baseline: 2.7101x; 1.0751x over previous
//
#include <hip/hip_runtime.h>

#define HIPPO_N 256
#define HIPPO_L 2048
#define CHUNKS  16
#define CSTEPS  128   // HIPPO_L / CHUNKS
#define NCOLS   257   // 256 basis columns + 1 u-driven column

// workspace layout (float offsets)
#define WS_PHI    0                                   // [CHUNKS][N][N]  Phi[g][j][i]
#define WS_Y0     (CHUNKS * HIPPO_N * HIPPO_N)        // [CHUNKS][N]
#define WS_R      (WS_Y0 + CHUNKS * HIPPO_N)          // [L][N]
#define WS_PRED0  (WS_R + HIPPO_L * HIPPO_N)          // [L]
#define WS_CIN    (WS_PRED0 + HIPPO_L)                // [CHUNKS][N]
#define WS_TOTAL  (WS_CIN + CHUNKS * HIPPO_N)

// ---------------------------------------------------------------------------
// HiPPO-LegS structured step (validated rounds 1/5):
//   A[i,j] = -T_i T_j (i>j), A[i,i]=-(i+1), T_i=sqrt(2i+1), B=T
//   c' = (I - A/2t)^{-1}((I + A/2t) c + (T/t) u)
// Joint formulation: walking rows i=0..255 with state (P,Q):
//   P_{i+1} = P_i + T_i c_i
//   vt_i    = alpha_i - T_i P_i,  alpha_i = c_i(2t-i-1) + 2u T_i
//   Q_{i+1} = q_i Q_i + T_i rho_i vt_i = p_i P_i + q_i Q_i + s_i
//     rho_i = 1/(2t+i+1), p_i = -(2i+1) rho_i, q_i = (2t-i) rho_i,
//     s_i = T_i rho_i alpha_i,  beta_i = T_i c_i
//   x_i (new c_i) = rho_i (alpha_i - T_i (P_i + Q_i))
// (P,Q) transition is lower-triangular affine -> single 4-var wave scan.
// Combine(left l, right r): beta=l.b+r.b; p=r.p+r.q*l.p; q=r.q*l.q;
//                           s=r.p*l.b + r.q*l.s + r.s.
// ---------------------------------------------------------------------------

#define SCAN_STAGE(D)                                              \
    {                                                              \
        float Bw = __shfl_up(B, (D), 64);                          \
        float Pw = __shfl_up(Pc, (D), 64);                         \
        float Qw = __shfl_up(Qc, (D), 64);                         \
        float Sw = __shfl_up(S, (D), 64);                          \
        if (lane >= (D)) {                                         \
            S  = Pc * Bw + Qc * Sw + S;                            \
            Pc = Pc + Qc * Pw;                                     \
            Qc = Qc * Qw;                                          \
            B  = B + Bw;                                           \
        }                                                          \
    }

// Phase 1: one wave = (chunk g, column j). Basis columns propagate e_j with
// u=0 (-> Phi column + R sensitivities); column 256 propagates zero state
// with real u (-> y0 + pred0 incl. direct term).
__global__ __launch_bounds__(256, 1)
void hippo_phase1(const float* __restrict__ u, float* __restrict__ ws) {
    const int lane = threadIdx.x & 63;
    const int wave = threadIdx.x >> 6;
    const int task = blockIdx.x * 4 + wave;
    if (task >= CHUNKS * NCOLS) return;
    const int g = task / NCOLS;
    const int j = task - g * NCOLS;
    const bool is_u = (j == HIPPO_N);
    const int i0 = lane * 4;

    float T[4], T2[4], fi[4], fi1[4], gv[4];
#pragma unroll
    for (int k = 0; k < 4; ++k) {
        const float f = (float)(i0 + k);
        const float ip1 = f + 1.0f;
        T2[k] = 2.0f * f + 1.0f;
        T[k] = sqrtf(T2[k]);
        fi[k] = f;
        fi1[k] = ip1;
        gv[k] = -T[k] * (ip1 + 65536.0f - ip1 * ip1);
    }

    float c[4];
#pragma unroll
    for (int k = 0; k < 4; ++k) c[k] = (!is_u && (i0 + k) == j) ? 1.0f : 0.0f;

    const int tbase = g * CSTEPS;
    float u_nxt = is_u ? u[tbase] : 0.0f;

    for (int tl = 0; tl < CSTEPS; ++tl) {
        const int t = tbase + tl + 1;
        const float u_t = u_nxt;
        if (is_u) {
            const int nxt = tbase + tl + 1;
            u_nxt = u[nxt < HIPPO_L ? nxt : HIPPO_L - 1];
        }
        const float two_t = 2.0f * (float)t;
        const float u2 = 2.0f * u_t;

        // per-row transition constants
        float beta[4], pp[4], qq[4], ss[4], rho[4], alpha[4];
#pragma unroll
        for (int k = 0; k < 4; ++k) {
            rho[k]   = __builtin_amdgcn_rcpf(two_t + fi1[k]);
            beta[k]  = T[k] * c[k];
            pp[k]    = -T2[k] * rho[k];
            qq[k]    = (two_t - fi[k]) * rho[k];
            alpha[k] = c[k] * (two_t - fi1[k]) + u2 * T[k];
            ss[k]    = T[k] * rho[k] * alpha[k];
        }

        // local composition of this lane's 4 row maps (left-to-right)
        float B = beta[0], Pc = pp[0], Qc = qq[0], S = ss[0];
#pragma unroll
        for (int k = 1; k < 4; ++k) {
            S  = pp[k] * B + qq[k] * S + ss[k];
            Pc = pp[k] + qq[k] * Pc;
            Qc = qq[k] * Qc;
            B  = B + beta[k];
        }

        // wave-inclusive scan of affine composites
        SCAN_STAGE(1)
        SCAN_STAGE(2)
        SCAN_STAGE(4)
        SCAN_STAGE(8)
        SCAN_STAGE(16)
        SCAN_STAGE(32)

        // exclusive incoming state: composite of lanes < lane applied to (0,0)
        float Pin = __shfl_up(B, 1, 64);
        float Qin = __shfl_up(S, 1, 64);
        if (lane == 0) { Pin = 0.f; Qin = 0.f; }

        // apply rows: new state + output functional
        float G = 0.f, P = Pin, Q = Qin;
#pragma unroll
        for (int k = 0; k < 4; ++k) {
            const float x = rho[k] * (alpha[k] - T[k] * (P + Q));
            G = fmaf(gv[k], x, G);
            const float Qn = pp[k] * P + qq[k] * Q + ss[k];  // uses OLD P
            P = P + beta[k];
            Q = Qn;
            c[k] = x;
        }
#pragma unroll
        for (int d = 32; d >= 1; d >>= 1) G += __shfl_xor(G, d, 64);

        if (lane == 0) {
            const float denom = two_t - 65536.0f;
            const float f = (t == 1) ? 1.0f : 2.0f;
            const float val = f * (G / denom);
            if (is_u)
                ws[WS_PRED0 + tbase + tl] = val + ((two_t + 65536.0f) / denom) * u_t;
            else
                ws[WS_R + (size_t)(tbase + tl) * HIPPO_N + j] = val;
        }
    }

    // final chunk state -> Phi column / y0
    float4 cv; cv.x = c[0]; cv.y = c[1]; cv.z = c[2]; cv.w = c[3];
    if (is_u)
        *(float4*)(ws + WS_Y0 + g * HIPPO_N + i0) = cv;
    else
        *(float4*)(ws + WS_PHI + ((size_t)(g * HIPPO_N + j)) * HIPPO_N + i0) = cv;
}

// Phase 2: serial chunk composition cin[g+1] = Phi_g cin[g] + y0[g].
// 4 waves split the j-range; each lane owns 4 rows via float4 loads; full
// unroll keeps ~24+ loads in flight per thread (latency*outstanding BW fix).
__global__ __launch_bounds__(256, 1)
void hippo_phase2(float* __restrict__ ws) {
    __shared__ float cs[HIPPO_N];
    __shared__ float partial[4][HIPPO_N];
    const int tid = threadIdx.x;
    const int wv = tid >> 6;
    const int ln = tid & 63;
    const int r0 = 4 * ln;

    float c = 0.f;  // this thread's row value (row = tid)
    for (int g = 0; g < CHUNKS; ++g) {
        ws[WS_CIN + g * HIPPO_N + tid] = c;
        cs[tid] = c;
        __syncthreads();
        if (g < CHUNKS - 1) {
            const float* P = ws + WS_PHI + (size_t)g * HIPPO_N * HIPPO_N;
            float a0 = 0.f, a1 = 0.f, a2 = 0.f, a3 = 0.f;
#pragma unroll
            for (int jj = 0; jj < 64; ++jj) {
                const int j = 64 * wv + jj;
                const float4 p = *(const float4*)(P + (size_t)j * HIPPO_N + r0);
                const float csj = cs[j];
                a0 = fmaf(p.x, csj, a0);
                a1 = fmaf(p.y, csj, a1);
                a2 = fmaf(p.z, csj, a2);
                a3 = fmaf(p.w, csj, a3);
            }
            float4 pv; pv.x = a0; pv.y = a1; pv.z = a2; pv.w = a3;
            *(float4*)&partial[wv][r0] = pv;
            __syncthreads();
            c = ws[WS_Y0 + g * HIPPO_N + tid] + partial[0][tid] + partial[1][tid]
                + partial[2][tid] + partial[3][tid];
        }
        __syncthreads();
    }
}

// Phase 3: pred_t = pred0_t + R[t,:] . cin[chunk(t)]
__global__ __launch_bounds__(256, 1)
void hippo_phase3(float* __restrict__ out, const float* __restrict__ ws) {
    const int lane = threadIdx.x & 63;
    const int wave = threadIdx.x >> 6;
    const int t = blockIdx.x * 4 + wave;
    if (t >= HIPPO_L) return;
    const int g = t / CSTEPS;
    const float* Rr = ws + WS_R + (size_t)t * HIPPO_N;
    const float* ci = ws + WS_CIN + g * HIPPO_N;
    const int i0 = lane * 4;
    const float4 r = *(const float4*)(Rr + i0);
    const float4 cv = *(const float4*)(ci + i0);
    float s = r.x * cv.x + r.y * cv.y + r.z * cv.z + r.w * cv.w;
#pragma unroll
    for (int d = 32; d >= 1; d >>= 1) s += __shfl_xor(s, d, 64);
    if (lane == 0) out[t] = ws[WS_PRED0 + t] + s;
}

// ---------------------------------------------------------------------------
// Fallback: round-1 single-wave serial scan (only if ws too small).
// ---------------------------------------------------------------------------
__global__ __launch_bounds__(64, 1)
void hippo_scan_serial(const float* __restrict__ u, float* __restrict__ out) {
    const int lane = threadIdx.x & 63;
    const int i0 = lane * 4;
    float T[4], gv[4], fi1[4];
#pragma unroll
    for (int k = 0; k < 4; ++k) {
        const float fi = (float)(i0 + k);
        const float ip1 = fi + 1.0f;
        T[k] = sqrtf(2.0f * fi + 1.0f);
        fi1[k] = ip1;
        gv[k] = -T[k] * (ip1 + 65536.0f - ip1 * ip1);
    }
    float c[4] = {0.f, 0.f, 0.f, 0.f};
    float u_nxt = u[0];
    for (int t = 1; t <= HIPPO_L; ++t) {
        const float u_t = u_nxt;
        u_nxt = u[t < HIPPO_L ? t : HIPPO_L - 1];
        const float two_t = 2.0f * (float)t;
        float pl[4]; float run = 0.f;
#pragma unroll
        for (int k = 0; k < 4; ++k) { pl[k] = run; run += T[k] * c[k]; }
        float inc = run;
#pragma unroll
        for (int d = 1; d < 64; d <<= 1) {
            float w = __shfl_up(inc, d, 64);
            if (lane >= d) inc += w;
        }
        const float Pbase = inc - run;
        float vt[4], rho[4];
#pragma unroll
        for (int k = 0; k < 4; ++k) {
            const float P = Pbase + pl[k];
            vt[k] = c[k] * (two_t - fi1[k]) - T[k] * P + 2.0f * u_t * T[k];
            rho[k] = 1.0f / (two_t + fi1[k]);
        }
        float al[4], el[4]; float Aacc = 1.f, Eacc = 0.f;
#pragma unroll
        for (int k = 0; k < 4; ++k) {
            al[k] = Aacc; el[k] = Eacc;
            const float a = (two_t - (fi1[k] - 1.0f)) * rho[k];
            const float e = T[k] * vt[k] * rho[k];
            Eacc = a * Eacc + e; Aacc = a * Aacc;
        }
        float Ai = Aacc, Ei = Eacc;
#pragma unroll
        for (int d = 1; d < 64; d <<= 1) {
            float Aw = __shfl_up(Ai, d, 64);
            float Ew = __shfl_up(Ei, d, 64);
            if (lane >= d) { Ei = Ai * Ew + Ei; Ai = Ai * Aw; }
        }
        float Qs = __shfl_up(Ei, 1, 64);
        if (lane == 0) Qs = 0.f;
        float s = 0.f;
#pragma unroll
        for (int k = 0; k < 4; ++k) {
            const float Q = al[k] * Qs + el[k];
            const float x = (vt[k] - T[k] * Q) * rho[k];
            c[k] = x; s += gv[k] * x;
        }
#pragma unroll
        for (int d = 32; d >= 1; d >>= 1) s += __shfl_xor(s, d, 64);
        if (lane == 0) {
            const float denom = two_t - 65536.0f;
            const float f = (t == 1) ? 1.0f : 2.0f;
            out[t - 1] = f * (s / denom) + ((two_t + 65536.0f) / denom) * u_t;
        }
    }
}

extern "C" void kernel_launch(void* const* d_in, const int* in_sizes, int n_in,
                              void* d_out, int out_size, void* d_ws, size_t ws_size,
                              hipStream_t stream) {
    (void)in_sizes; (void)n_in; (void)out_size;
    const float* u = (const float*)d_in[0];
    float* out = (float*)d_out;

    if (ws_size < (size_t)WS_TOTAL * sizeof(float)) {
        hippo_scan_serial<<<dim3(1), dim3(64), 0, stream>>>(u, out);
        return;
    }
    float* ws = (float*)d_ws;
    const int p1_blocks = (CHUNKS * NCOLS + 3) / 4;
    hippo_phase1<<<dim3(p1_blocks), dim3(256), 0, stream>>>(u, ws);
    hippo_phase2<<<dim3(1), dim3(256), 0, stream>>>(ws);
    hippo_phase3<<<dim3(HIPPO_L / 4), dim3(256), 0, stream>>>(out, ws);
}

// Round 7
// 817.120 us; speedup vs baseline: 2.8912x; 1.0668x over previous
//
#include <hip/hip_runtime.h>

#define HIPPO_N 256
#define HIPPO_L 2048
#define CHUNKS  16
#define CSTEPS  128   // HIPPO_L / CHUNKS
#define NCOLS   257   // 256 basis columns + 1 u-driven column

// workspace layout (float offsets)
#define WS_PHI    0                                   // [CHUNKS][N][N]  Phi[g][j][i]
#define WS_Y0     (CHUNKS * HIPPO_N * HIPPO_N)        // [CHUNKS][N]
#define WS_R      (WS_Y0 + CHUNKS * HIPPO_N)          // [L][N]
#define WS_PRED0  (WS_R + HIPPO_L * HIPPO_N)          // [L]
#define WS_CIN    (WS_PRED0 + HIPPO_L)                // [CHUNKS][N]
#define WS_TOTAL  (WS_CIN + CHUNKS * HIPPO_N)

// DPP controls (gfx9/CDNA): row_shr:n = 0x110+n, wave_shr:1 = 0x138,
// row_bcast15 = 0x142, row_bcast31 = 0x143.
template<int CTRL, int RMASK>
__device__ __forceinline__ float dpp_mov(float old_v, float src) {
    return __int_as_float(__builtin_amdgcn_update_dpp(
        __float_as_int(old_v), __float_as_int(src), CTRL, RMASK, 0xF, false));
}

// ---------------------------------------------------------------------------
// HiPPO-LegS structured step (formulation validated rounds 1/5/6):
//   P_{i+1} = P_i + beta_i                    beta_i = T_i c_i
//   Q_{i+1} = p_i P_i + q_i Q_i + s_i
//     rho_i = 1/(2t+i+1), p_i = -(2i+1)rho_i, q_i = (2t-i)rho_i,
//     alpha_i = c_i(2t-i-1) + 2u T_i, s_i = T_i rho_i alpha_i
//   x_i (new c_i) = rho_i (alpha_i - T_i (P_i + Q_i))
// Affine composite vars (B, Pc, Qc, S); combine(current=right, left w):
//   S=Pc*Bw+Qc*Sw+S; Pc=Pc+Qc*Pw; Qc=Qc*Qw; B=B+Bw.
// Wave64 inclusive scan entirely in DPP (no DS ops):
//   row_shr 1,2,4,8 ; row_bcast15 (rows 1,3) ; row_bcast31 (rows 2,3).
// ---------------------------------------------------------------------------

#define AFF_STAGE(CTRL, RMASK)                                     \
    {                                                              \
        const float Bw = dpp_mov<CTRL, RMASK>(0.0f, B);            \
        const float Pw = dpp_mov<CTRL, RMASK>(0.0f, Pc);           \
        const float Qw = dpp_mov<CTRL, RMASK>(1.0f, Qc);           \
        const float Sw = dpp_mov<CTRL, RMASK>(0.0f, S);            \
        S  = fmaf(Pc, Bw, fmaf(Qc, Sw, S));                        \
        Pc = fmaf(Qc, Pw, Pc);                                     \
        Qc = Qc * Qw;                                              \
        B  = B + Bw;                                               \
    }

#define SUM_STAGE(CTRL, RMASK) G += dpp_mov<CTRL, RMASK>(0.0f, G);

// Phase 1: one wave = (chunk g, column j). Basis columns propagate e_j with
// u=0 (-> Phi column + R sensitivities); column 256 propagates zero state
// with real u (-> y0 + pred0 incl. direct term).
__global__ __launch_bounds__(256, 1)
void hippo_phase1(const float* __restrict__ u, float* __restrict__ ws) {
    const int lane = threadIdx.x & 63;
    const int wave = threadIdx.x >> 6;
    const int task = blockIdx.x * 4 + wave;
    if (task >= CHUNKS * NCOLS) return;
    const int g = task / NCOLS;
    const int j = task - g * NCOLS;
    const bool is_u = (j == HIPPO_N);
    const int i0 = lane * 4;

    float T[4], T2[4], fi[4], fi1[4], gv[4];
#pragma unroll
    for (int k = 0; k < 4; ++k) {
        const float f = (float)(i0 + k);
        const float ip1 = f + 1.0f;
        T2[k] = 2.0f * f + 1.0f;
        T[k] = sqrtf(T2[k]);
        fi[k] = f;
        fi1[k] = ip1;
        gv[k] = -T[k] * (ip1 + 65536.0f - ip1 * ip1);
    }

    float c[4];
#pragma unroll
    for (int k = 0; k < 4; ++k) c[k] = (!is_u && (i0 + k) == j) ? 1.0f : 0.0f;

    const int tbase = g * CSTEPS;
    float u_nxt = is_u ? u[tbase] : 0.0f;

    for (int tl = 0; tl < CSTEPS; ++tl) {
        const int t = tbase + tl + 1;
        const float u_t = u_nxt;
        if (is_u) {
            const int nxt = tbase + tl + 1;
            u_nxt = u[nxt < HIPPO_L ? nxt : HIPPO_L - 1];
        }
        const float two_t = 2.0f * (float)t;
        const float u2 = 2.0f * u_t;

        // per-row transition constants
        float beta[4], pp[4], qq[4], ss[4], rho[4], alpha[4];
#pragma unroll
        for (int k = 0; k < 4; ++k) {
            rho[k]   = __builtin_amdgcn_rcpf(two_t + fi1[k]);
            beta[k]  = T[k] * c[k];
            pp[k]    = -T2[k] * rho[k];
            qq[k]    = (two_t - fi[k]) * rho[k];
            alpha[k] = c[k] * (two_t - fi1[k]) + u2 * T[k];
            ss[k]    = T[k] * rho[k] * alpha[k];
        }

        // local composition of this lane's 4 row maps (left-to-right)
        float B = beta[0], Pc = pp[0], Qc = qq[0], S = ss[0];
#pragma unroll
        for (int k = 1; k < 4; ++k) {
            S  = fmaf(pp[k], B, fmaf(qq[k], S, ss[k]));
            Pc = fmaf(qq[k], Pc, pp[k]);
            Qc = qq[k] * Qc;
            B  = B + beta[k];
        }

        // wave-inclusive scan of affine composites — pure DPP (VALU)
        AFF_STAGE(0x111, 0xF)   // row_shr:1
        AFF_STAGE(0x112, 0xF)   // row_shr:2
        AFF_STAGE(0x114, 0xF)   // row_shr:4
        AFF_STAGE(0x118, 0xF)   // row_shr:8
        AFF_STAGE(0x142, 0xA)   // row_bcast15 -> rows 1,3
        AFF_STAGE(0x143, 0xC)   // row_bcast31 -> rows 2,3

        // exclusive incoming state via wave_shr:1 (lane0 -> identity 0)
        float P = dpp_mov<0x138, 0xF>(0.0f, B);
        float Q = dpp_mov<0x138, 0xF>(0.0f, S);

        // apply rows: new state + output functional
        float G = 0.f;
#pragma unroll
        for (int k = 0; k < 4; ++k) {
            const float x = rho[k] * (alpha[k] - T[k] * (P + Q));
            G = fmaf(gv[k], x, G);
            const float Qn = fmaf(pp[k], P, fmaf(qq[k], Q, ss[k]));  // uses OLD P
            P = P + beta[k];
            Q = Qn;
            c[k] = x;
        }
        // wave sum of G via DPP scan; total lands on lane 63
        SUM_STAGE(0x111, 0xF)
        SUM_STAGE(0x112, 0xF)
        SUM_STAGE(0x114, 0xF)
        SUM_STAGE(0x118, 0xF)
        SUM_STAGE(0x142, 0xA)
        SUM_STAGE(0x143, 0xC)

        if (lane == 63) {
            const float rden = __builtin_amdgcn_rcpf(two_t - 65536.0f);
            const float f = (t == 1) ? 1.0f : 2.0f;
            const float val = f * G * rden;
            if (is_u)
                ws[WS_PRED0 + tbase + tl] = val + (two_t + 65536.0f) * rden * u_t;
            else
                ws[WS_R + (size_t)(tbase + tl) * HIPPO_N + j] = val;
        }
    }

    // final chunk state -> Phi column / y0
    float4 cv; cv.x = c[0]; cv.y = c[1]; cv.z = c[2]; cv.w = c[3];
    if (is_u)
        *(float4*)(ws + WS_Y0 + g * HIPPO_N + i0) = cv;
    else
        *(float4*)(ws + WS_PHI + ((size_t)(g * HIPPO_N + j)) * HIPPO_N + i0) = cv;
}

// Phase 2: serial chunk composition cin[g+1] = Phi_g cin[g] + y0[g].
// 4 waves split the j-range; each lane owns 4 rows via float4 loads; full
// unroll keeps many loads in flight (latency*outstanding BW).
__global__ __launch_bounds__(256, 1)
void hippo_phase2(float* __restrict__ ws) {
    __shared__ float cs[HIPPO_N];
    __shared__ float partial[4][HIPPO_N];
    const int tid = threadIdx.x;
    const int wv = tid >> 6;
    const int ln = tid & 63;
    const int r0 = 4 * ln;

    float c = 0.f;  // this thread's row value (row = tid)
    for (int g = 0; g < CHUNKS; ++g) {
        ws[WS_CIN + g * HIPPO_N + tid] = c;
        cs[tid] = c;
        __syncthreads();
        if (g < CHUNKS - 1) {
            const float* P = ws + WS_PHI + (size_t)g * HIPPO_N * HIPPO_N;
            float a0 = 0.f, a1 = 0.f, a2 = 0.f, a3 = 0.f;
#pragma unroll
            for (int jj = 0; jj < 64; ++jj) {
                const int j = 64 * wv + jj;
                const float4 p = *(const float4*)(P + (size_t)j * HIPPO_N + r0);
                const float csj = cs[j];
                a0 = fmaf(p.x, csj, a0);
                a1 = fmaf(p.y, csj, a1);
                a2 = fmaf(p.z, csj, a2);
                a3 = fmaf(p.w, csj, a3);
            }
            float4 pv; pv.x = a0; pv.y = a1; pv.z = a2; pv.w = a3;
            *(float4*)&partial[wv][r0] = pv;
            __syncthreads();
            c = ws[WS_Y0 + g * HIPPO_N + tid] + partial[0][tid] + partial[1][tid]
                + partial[2][tid] + partial[3][tid];
        }
        __syncthreads();
    }
}

// Phase 3: pred_t = pred0_t + R[t,:] . cin[chunk(t)]
__global__ __launch_bounds__(256, 1)
void hippo_phase3(float* __restrict__ out, const float* __restrict__ ws) {
    const int lane = threadIdx.x & 63;
    const int wave = threadIdx.x >> 6;
    const int t = blockIdx.x * 4 + wave;
    if (t >= HIPPO_L) return;
    const int g = t / CSTEPS;
    const float* Rr = ws + WS_R + (size_t)t * HIPPO_N;
    const float* ci = ws + WS_CIN + g * HIPPO_N;
    const int i0 = lane * 4;
    const float4 r = *(const float4*)(Rr + i0);
    const float4 cv = *(const float4*)(ci + i0);
    float s = r.x * cv.x + r.y * cv.y + r.z * cv.z + r.w * cv.w;
#pragma unroll
    for (int d = 32; d >= 1; d >>= 1) s += __shfl_xor(s, d, 64);
    if (lane == 0) out[t] = ws[WS_PRED0 + t] + s;
}

// ---------------------------------------------------------------------------
// Fallback: round-1 single-wave serial scan (only if ws too small).
// ---------------------------------------------------------------------------
__global__ __launch_bounds__(64, 1)
void hippo_scan_serial(const float* __restrict__ u, float* __restrict__ out) {
    const int lane = threadIdx.x & 63;
    const int i0 = lane * 4;
    float T[4], gv[4], fi1[4];
#pragma unroll
    for (int k = 0; k < 4; ++k) {
        const float fi = (float)(i0 + k);
        const float ip1 = fi + 1.0f;
        T[k] = sqrtf(2.0f * fi + 1.0f);
        fi1[k] = ip1;
        gv[k] = -T[k] * (ip1 + 65536.0f - ip1 * ip1);
    }
    float c[4] = {0.f, 0.f, 0.f, 0.f};
    float u_nxt = u[0];
    for (int t = 1; t <= HIPPO_L; ++t) {
        const float u_t = u_nxt;
        u_nxt = u[t < HIPPO_L ? t : HIPPO_L - 1];
        const float two_t = 2.0f * (float)t;
        float pl[4]; float run = 0.f;
#pragma unroll
        for (int k = 0; k < 4; ++k) { pl[k] = run; run += T[k] * c[k]; }
        float inc = run;
#pragma unroll
        for (int d = 1; d < 64; d <<= 1) {
            float w = __shfl_up(inc, d, 64);
            if (lane >= d) inc += w;
        }
        const float Pbase = inc - run;
        float vt[4], rho[4];
#pragma unroll
        for (int k = 0; k < 4; ++k) {
            const float P = Pbase + pl[k];
            vt[k] = c[k] * (two_t - fi1[k]) - T[k] * P + 2.0f * u_t * T[k];
            rho[k] = 1.0f / (two_t + fi1[k]);
        }
        float al[4], el[4]; float Aacc = 1.f, Eacc = 0.f;
#pragma unroll
        for (int k = 0; k < 4; ++k) {
            al[k] = Aacc; el[k] = Eacc;
            const float a = (two_t - (fi1[k] - 1.0f)) * rho[k];
            const float e = T[k] * vt[k] * rho[k];
            Eacc = a * Eacc + e; Aacc = a * Aacc;
        }
        float Ai = Aacc, Ei = Eacc;
#pragma unroll
        for (int d = 1; d < 64; d <<= 1) {
            float Aw = __shfl_up(Ai, d, 64);
            float Ew = __shfl_up(Ei, d, 64);
            if (lane >= d) { Ei = Ai * Ew + Ei; Ai = Ai * Aw; }
        }
        float Qs = __shfl_up(Ei, 1, 64);
        if (lane == 0) Qs = 0.f;
        float s = 0.f;
#pragma unroll
        for (int k = 0; k < 4; ++k) {
            const float Q = al[k] * Qs + el[k];
            const float x = (vt[k] - T[k] * Q) * rho[k];
            c[k] = x; s += gv[k] * x;
        }
#pragma unroll
        for (int d = 32; d >= 1; d >>= 1) s += __shfl_xor(s, d, 64);
        if (lane == 0) {
            const float denom = two_t - 65536.0f;
            const float f = (t == 1) ? 1.0f : 2.0f;
            out[t - 1] = f * (s / denom) + ((two_t + 65536.0f) / denom) * u_t;
        }
    }
}

extern "C" void kernel_launch(void* const* d_in, const int* in_sizes, int n_in,
                              void* d_out, int out_size, void* d_ws, size_t ws_size,
                              hipStream_t stream) {
    (void)in_sizes; (void)n_in; (void)out_size;
    const float* u = (const float*)d_in[0];
    float* out = (float*)d_out;

    if (ws_size < (size_t)WS_TOTAL * sizeof(float)) {
        hippo_scan_serial<<<dim3(1), dim3(64), 0, stream>>>(u, out);
        return;
    }
    float* ws = (float*)d_ws;
    const int p1_blocks = (CHUNKS * NCOLS + 3) / 4;
    hippo_phase1<<<dim3(p1_blocks), dim3(256), 0, stream>>>(u, ws);
    hippo_phase2<<<dim3(1), dim3(256), 0, stream>>>(ws);
    hippo_phase3<<<dim3(HIPPO_L / 4), dim3(256), 0, stream>>>(out, ws);
}